// Round 12
// baseline (168.803 us; speedup 1.0000x reference)
//
#include <hip/hip_runtime.h>
#include <hip/hip_bf16.h>

// Fused 2-layer SimpleRNN, int8 MFMA (16x16x64, i32 accumulate), fp32 dequant.
// Round 26: HALVE MFMA COUNT via K=64 i8 MFMA on the R22/R25 structure.
//   Additive cost model confirmed across R16/R17/R22/R24/R25:
//     iter = 43*N_mfma + 2*N_valu   (R22: 24*43 + 480 = 1512 ~ 1508 meas)
//   Only big lever left: N_mfma. mfma_i32_16x16x64_i8 does K=64 in ONE
//   instruction -> 4 MFMAs per 64x64 matmul; Wx2/Wh2 share one quant
//   scale so layer-2 chains EXACTLY in i32: 12 MFMAs/iter (-516 cyc).
//   Quantize h: tanh in packed f16, then pk_fma(r,127,1152) puts
//   round(127*tanh) in the f16 mantissa low byte (f16 ulp=1 on [1024,2048)
//   => RNE to integer grid); v_perm gathers 4 bytes, XOR 0x80 flips bias
//   to signed i8. Dequant: v_cvt_f32_i32 + fma(scale, v, xp/b2).
//   C->B identity survives: B byte j of lane(q,c) needs u=(j>>2)*16+4q+
//   (j&3) = C-frag (j>>2) reg (j&3) -> h1q = {quant(frag0..3)}, no shuffle.
//   Precision: h err 0.5/127 = 2^-8 (same as the bf16-era h path that
//   measured absmax 0.0039 for 22 rounds); weights ~2^-9 rel; i32 exact.
// Grid 1024 x 64 threads = 1024 waves = 1 wave/SIMD.

#define BATCH 16384
#define SEQ   80
#define EMBED 100
#define UNITS 64
#define ROWS  16
#define VOCAB 10000

typedef __attribute__((ext_vector_type(4))) float f32x4;
typedef __attribute__((ext_vector_type(2))) float f32x2;
typedef __attribute__((ext_vector_type(4))) int   i32x4;

// packed half2 in the builtin's own type
using h2t = decltype(__builtin_amdgcn_cvt_pkrtz(0.f, 0.f));

// scalar fp32 tanh for the once-only epilogue
static __device__ __forceinline__ f32x2 tanh2(f32x2 x) {
    f32x2 u = x * x;
    f32x2 w = x * u;
    f32x2 p = u * 0.13333333f + (-0.33333333f);
    return w * p + x;
}

// xp[v][u] = b1[u] + sum_k emb[v][k] * Wx1[k][u]   (fp32, exact)
__global__ __launch_bounds__(256) void xp_prep(const float* __restrict__ emb,
                                               const float* __restrict__ Wx1,
                                               const float* __restrict__ b1,
                                               float* __restrict__ xp) {
    const int v = blockIdx.x * 4 + (threadIdx.x >> 6);
    const int u = threadIdx.x & 63;
    const float* er = emb + (size_t)v * EMBED;
    const float* wc = Wx1 + u;
    float acc = b1[u];
#pragma unroll 5
    for (int k4 = 0; k4 < EMBED / 4; ++k4) {
        f32x4 e = *reinterpret_cast<const f32x4*>(er + k4 * 4);
        acc += e[0] * wc[(k4 * 4 + 0) * UNITS];
        acc += e[1] * wc[(k4 * 4 + 1) * UNITS];
        acc += e[2] * wc[(k4 * 4 + 2) * UNITS];
        acc += e[3] * wc[(k4 * 4 + 3) * UNITS];
    }
    xp[(size_t)v * UNITS + u] = acc;
}

__global__ __launch_bounds__(64, 1)
void rnn_fused(const int* __restrict__ tokens,
               const float* __restrict__ xpT,
               const float* __restrict__ Wh1,
               const float* __restrict__ Wx2,
               const float* __restrict__ Wh2,
               const float* __restrict__ b2,
               const float* __restrict__ Wd,
               const float* __restrict__ bd,
               float* __restrict__ out)
{
    __shared__ int tokL[ROWS][SEQ + 1];

    const int lane = threadIdx.x;    // single wave
    const int c    = lane & 15;      // batch col (B/C n-index)
    const int q    = lane >> 4;      // quad
    const int rowBase = blockIdx.x * ROWS;

    for (int i = lane; i < ROWS * SEQ; i += 64) {
        int r = i / SEQ, tt = i - r * SEQ;
        tokL[r][tt] = tokens[rowBase * SEQ + i];
    }
    __syncthreads();

    // ---- weight quantization (one-time) ----
    // A-frag byte j (dword j>>2, byte j&3) <-> u = (j>>2)*16 + q*4 + (j&3)
    auto maxW = [&](const float* W) -> float {
        float wmax = 1e-20f;
#pragma unroll
        for (int mt = 0; mt < 4; ++mt)
#pragma unroll
            for (int j = 0; j < 16; ++j) {
                int u = ((j >> 2) << 4) + q * 4 + (j & 3);
                wmax = fmaxf(wmax, fabsf(W[u * UNITS + mt * 16 + c]));
            }
#pragma unroll
        for (int off = 1; off < 64; off <<= 1)
            wmax = fmaxf(wmax, __shfl_xor(wmax, off));
        return wmax;
    };
    auto quantW = [&](const float* W, float sw, i32x4 (&dst)[4]) {
#pragma unroll
        for (int mt = 0; mt < 4; ++mt) {
            i32x4 d;
#pragma unroll
            for (int dd = 0; dd < 4; ++dd) {
                int b = 0;
#pragma unroll
                for (int bb = 0; bb < 4; ++bb) {
                    int u = dd * 16 + q * 4 + bb;
                    int qv = (int)rintf(W[u * UNITS + mt * 16 + c] * sw);
                    b |= (qv & 255) << (bb * 8);
                }
                d[dd] = b;
            }
            dst[mt] = d;
        }
    };

    i32x4 aq1[4], aq2x[4], aq2h[4];
    float m1 = maxW(Wh1);
    float m2 = fmaxf(maxW(Wx2), maxW(Wh2));   // SHARED scale: exact i32 chain
    float sw1 = 126.9f / m1, sw2 = 126.9f / m2;
    quantW(Wh1, sw1, aq1);
    quantW(Wx2, sw2, aq2x);
    quantW(Wh2, sw2, aq2h);
    const float s1 = 1.0f / (127.0f * sw1);
    const float s2 = 1.0f / (127.0f * sw2);

    f32x4 b2C[4];
#pragma unroll
    for (int mt = 0; mt < 4; ++mt)
#pragma unroll
        for (int r = 0; r < 4; ++r)
            b2C[mt][r] = b2[mt * 16 + q * 4 + r];

    // ---- packed-half tanh + int8 quant (magic-bias pack) ----
    const h2t kC1h = __builtin_amdgcn_cvt_pkrtz( 0.13333333f,  0.13333333f);
    const h2t kC0h = __builtin_amdgcn_cvt_pkrtz(-0.33333333f, -0.33333333f);
    const h2t k127 = __builtin_amdgcn_cvt_pkrtz(127.0f, 127.0f);
    const h2t kMag = __builtin_amdgcn_cvt_pkrtz(1152.0f, 1152.0f);  // 1024+128

    // f32x4 -> tanh -> round(127*tanh) as 4 signed bytes in one dword
    auto quant_frag = [&](f32x4 v) -> int {
        h2t lo = __builtin_amdgcn_cvt_pkrtz(v[0], v[1]);
        h2t hi = __builtin_amdgcn_cvt_pkrtz(v[2], v[3]);
        h2t ulo = lo * lo,           uhi = hi * hi;
        h2t wlo = ulo * lo,          whi = uhi * hi;
        h2t plo = ulo * kC1h + kC0h, phi = uhi * kC1h + kC0h;
        h2t rlo = wlo * plo + lo,    rhi = whi * phi + hi;
        h2t qlo = rlo * k127 + kMag, qhi = rhi * k127 + kMag;  // int in mantissa
        unsigned pk = __builtin_amdgcn_perm(__builtin_bit_cast(unsigned, qhi),
                                            __builtin_bit_cast(unsigned, qlo),
                                            0x06040200u);      // b0,b2 of each
        return (int)(pk ^ 0x80808080u);                        // bias -> signed
    };

    // dequant: i32 frag -> fp32 with scale + addend
    auto dq = [&](i32x4 v, float s, f32x4 add) -> f32x4 {
        f32x4 r;
        r[0] = (float)v[0] * s + add[0];
        r[1] = (float)v[1] * s + add[1];
        r[2] = (float)v[2] * s + add[2];
        r[3] = (float)v[3] * s + add[3];
        return r;
    };

    const int* tokC = &tokL[c][0];

    auto gatherXP = [&](int tk, f32x4 (&dst)[4]) {
        const float* p = xpT + (unsigned)tk * UNITS + q * 4;
        dst[0] = *reinterpret_cast<const f32x4*>(p);
        dst[1] = *reinterpret_cast<const f32x4*>(p + 16);
        dst[2] = *reinterpret_cast<const f32x4*>(p + 32);
        dst[3] = *reinterpret_cast<const f32x4*>(p + 48);
    };

    const i32x4 kz = {0, 0, 0, 0};

    // state: h1q = quant(h1(t-1)), h2q = quant(h2(t-2)) entering iteration t
    i32x4 h1q = kz, h2q = kz;
    f32x4 xp0[4], xp1[4];
    int tkNext = 0;
    gatherXP(tokC[0], xp0);
    gatherXP(tokC[1], xp1);

    // skewed body for iteration t (1 <= t <= 79), 12 MFMAs:
    //   v1 = Wh1q . h1q           (i32)  -> h1(t)  = tanh(s1*v1 + xp(t))
    //   v2 = Wx2q.h1q + Wh2q.h2q  (i32)  -> h2(t-1)= tanh(s2*v2 + b2)
    auto body = [&](f32x4 (&xpS)[4], bool doPre, int tpn) {
        int tkUse = tkNext;              // token for xp(t+2), loaded last iter
        if (doPre) tkNext = tokC[tpn];   // ds_read for next iter
        i32x4 v1[4], v2[4];
#pragma unroll
        for (int mt = 0; mt < 4; ++mt)
            v1[mt] = __builtin_amdgcn_mfma_i32_16x16x64_i8(aq1[mt], h1q, kz, 0, 0, 0);
#pragma unroll
        for (int mt = 0; mt < 4; ++mt)
            v2[mt] = __builtin_amdgcn_mfma_i32_16x16x64_i8(aq2x[mt], h1q, kz, 0, 0, 0);
#pragma unroll
        for (int mt = 0; mt < 4; ++mt)
            v2[mt] = __builtin_amdgcn_mfma_i32_16x16x64_i8(aq2h[mt], h2q, v2[mt], 0, 0, 0);
        // h1(t): dequant with xp(t), tanh, quantize
        i32x4 nh1, nh2;
#pragma unroll
        for (int mt = 0; mt < 4; ++mt)
            nh1[mt] = quant_frag(dq(v1[mt], s1, xpS[mt]));
        if (doPre) gatherXP(tkUse, xpS);   // refill consumed buffer
        // h2(t-1): dequant with b2, tanh, quantize
#pragma unroll
        for (int mt = 0; mt < 4; ++mt)
            nh2[mt] = quant_frag(dq(v2[mt], s2, b2C[mt]));
        h1q = nh1;
        h2q = nh2;
    };

    // ---- t = 0 peeled: h1(0) = tanh(xp(0)); h2q stays 0 (== h2(-1)) ----
    {
        i32x4 nh1;
#pragma unroll
        for (int mt = 0; mt < 4; ++mt)
            nh1[mt] = quant_frag(xp0[mt]);
        h1q = nh1;
        gatherXP(tokC[2], xp0);
        tkNext = tokC[3];
    }

    // ---- t = 1..76 in parity pairs (xp(t) lives in buffer t&1) ----
#pragma unroll 1
    for (int tt = 1; tt <= 75; tt += 2) {
        body(xp1, true, tt + 3);   // t = tt   (odd):  uses xp1
        body(xp0, true, tt + 4);   // t = tt+1 (even): uses xp0
    }
    body(xp1, true, 80);   // t = 77: consumes tokC[79]; dummy-prefetch [80]
    body(xp0, false, 0);   // t = 78: uses xp(78)
    body(xp1, false, 0);   // t = 79: uses xp(79) -> h1q(79), h2q(78)

    // ---- epilogue: L2(79) + dense head, all in fp32 ----
    {
        i32x4 v2[4];
#pragma unroll
        for (int mt = 0; mt < 4; ++mt)
            v2[mt] = __builtin_amdgcn_mfma_i32_16x16x64_i8(aq2x[mt], h1q, kz, 0, 0, 0);
#pragma unroll
        for (int mt = 0; mt < 4; ++mt)
            v2[mt] = __builtin_amdgcn_mfma_i32_16x16x64_i8(aq2h[mt], h2q, v2[mt], 0, 0, 0);

        f32x4 wdC[4];
#pragma unroll
        for (int mt = 0; mt < 4; ++mt)
#pragma unroll
            for (int r = 0; r < 4; ++r)
                wdC[mt][r] = Wd[mt * 16 + q * 4 + r];
        const float bdv = bd[0];

        float p = 0.f;
#pragma unroll
        for (int mt = 0; mt < 4; ++mt) {
            f32x4 a = dq(v2[mt], s2, b2C[mt]);
            f32x2 lo = tanh2((f32x2){a[0], a[1]});
            f32x2 hi = tanh2((f32x2){a[2], a[3]});
            p += lo[0] * wdC[mt][0] + lo[1] * wdC[mt][1]
               + hi[0] * wdC[mt][2] + hi[1] * wdC[mt][3];
        }
        p += __shfl_xor(p, 16);
        p += __shfl_xor(p, 32);
        if (q == 0) {
            float x = p + bdv;
            out[rowBase + c] = __builtin_amdgcn_rcpf(1.0f + __expf(-x));
        }
    }
}

extern "C" void kernel_launch(void* const* d_in, const int* in_sizes, int n_in,
                              void* d_out, int out_size, void* d_ws, size_t ws_size,
                              hipStream_t stream) {
    const int*   tokens = (const int*)  d_in[0];
    const float* emb    = (const float*)d_in[1];
    const float* Wx1    = (const float*)d_in[2];
    const float* Wh1    = (const float*)d_in[3];
    const float* b1     = (const float*)d_in[4];
    const float* Wx2    = (const float*)d_in[5];
    const float* Wh2    = (const float*)d_in[6];
    const float* b2     = (const float*)d_in[7];
    const float* Wd     = (const float*)d_in[8];
    const float* bd     = (const float*)d_in[9];
    float* out = (float*)d_out;

    // xp = emb@Wx1 + b1 (2.56 MB in d_ws; ws has held >= this in all rounds)
    float* xp = (float*)d_ws;
    xp_prep<<<dim3(VOCAB / 4), dim3(256), 0, stream>>>(emb, Wx1, b1, xp);

    dim3 grid(BATCH / ROWS);  // 1024 blocks x 1 wave = 1 wave/SIMD
    dim3 block(64);
    rnn_fused<<<grid, block, 0, stream>>>(tokens, xp, Wh1, Wx2, Wh2, b2, Wd, bd, out);
}

// Round 13
// 131.131 us; speedup vs baseline: 1.2873x; 1.2873x over previous
//
#include <hip/hip_runtime.h>
#include <hip/hip_bf16.h>

// Fused 2-layer SimpleRNN, fp16 MFMA (16x16x32), fp32 accumulate.
// Round 27: RESTORE CHAMPION (R22/R25 structure, best = 50.24 us kernel).
//   R26 post-mortem: i8 K=64 halved MFMA cycles (MfmaUtil 24.4->7.1) but
//   the dequant->tanh->requant serial chain on the recurrence critical
//   path cost ~1100 cyc vs 516 saved. Final validated cost model:
//     iter = 43*N_mfma + 2*N_valu ; champion 24*43+480 = 1512 ~ 1508 meas
//   43 cyc/MFMA (single-wave issue/blocking) survived: SGB reorder (R20),
//   source pipelining (R19), asm packing (R21), 2-wave co-residency (R24,
//   exactly additive), 3 producer/consumer schemes (R14/R18/R23), and
//   fewer-heavier MFMAs (R26). N_mfma=24 is the f16 K=32 minimum for the
//   3 matmuls/step; N_valu~240 is packed-half minimal. This kernel sits
//   AT the structural floor => restoring it as the final answer.
// Grid 1024 x 64 threads = 1024 waves = 1 wave/SIMD.

#define BATCH 16384
#define SEQ   80
#define EMBED 100
#define UNITS 64
#define ROWS  16
#define VOCAB 10000

typedef __attribute__((ext_vector_type(8))) _Float16 f16x8;
typedef __attribute__((ext_vector_type(4))) float f32x4;
typedef __attribute__((ext_vector_type(2))) float f32x2;
typedef __attribute__((ext_vector_type(4))) int   i32x4;
typedef __attribute__((ext_vector_type(2))) int   i32x2;

// packed half2 in the builtin's own type (keeps clang type-happy)
using h2t = decltype(__builtin_amdgcn_cvt_pkrtz(0.f, 0.f));

// scalar fp32 tanh for the once-only epilogue
static __device__ __forceinline__ f32x2 tanh2(f32x2 x) {
    f32x2 u = x * x;
    f32x2 w = x * u;
    f32x2 p = u * 0.13333333f + (-0.33333333f);
    return w * p + x;
}

static __device__ __forceinline__ f16x8 ash(i32x4 v) {
    return __builtin_bit_cast(f16x8, v);
}

// xp[v][u] = b1[u] + sum_k emb[v][k] * Wx1[k][u]   (fp32, exact)
__global__ __launch_bounds__(256) void xp_prep(const float* __restrict__ emb,
                                               const float* __restrict__ Wx1,
                                               const float* __restrict__ b1,
                                               float* __restrict__ xp) {
    const int v = blockIdx.x * 4 + (threadIdx.x >> 6);
    const int u = threadIdx.x & 63;
    const float* er = emb + (size_t)v * EMBED;
    const float* wc = Wx1 + u;
    float acc = b1[u];
#pragma unroll 5
    for (int k4 = 0; k4 < EMBED / 4; ++k4) {
        f32x4 e = *reinterpret_cast<const f32x4*>(er + k4 * 4);
        acc += e[0] * wc[(k4 * 4 + 0) * UNITS];
        acc += e[1] * wc[(k4 * 4 + 1) * UNITS];
        acc += e[2] * wc[(k4 * 4 + 2) * UNITS];
        acc += e[3] * wc[(k4 * 4 + 3) * UNITS];
    }
    xp[(size_t)v * UNITS + u] = acc;
}

__global__ __launch_bounds__(64, 1)
void rnn_fused(const int* __restrict__ tokens,
               const float* __restrict__ xpT,
               const float* __restrict__ Wh1,
               const float* __restrict__ Wx2,
               const float* __restrict__ Wh2,
               const float* __restrict__ b2,
               const float* __restrict__ Wd,
               const float* __restrict__ bd,
               float* __restrict__ out)
{
    __shared__ int tokL[ROWS][SEQ + 1];

    const int lane = threadIdx.x;    // single wave
    const int c    = lane & 15;      // batch col (B/C n-index)
    const int q    = lane >> 4;      // quad
    const int rowBase = blockIdx.x * ROWS;

    for (int i = lane; i < ROWS * SEQ; i += 64) {
        int r = i / SEQ, tt = i - r * SEQ;
        tokL[r][tt] = tokens[rowBase * SEQ + i];
    }
    __syncthreads();

    // permuted-k weight A-frag loader: slot (kt,q,j) <-> u = 32kt+16(j>>2)+4q+(j&3)
    auto loadW = [&](const float* W, f16x8 (&dst)[2][4]) {
#pragma unroll
        for (int kt = 0; kt < 2; ++kt)
#pragma unroll
            for (int mt = 0; mt < 4; ++mt) {
                f16x8 v;
#pragma unroll
                for (int j = 0; j < 8; ++j) {
                    int u = kt * 32 + ((j >> 2) << 4) + q * 4 + (j & 3);
                    v[j] = (_Float16)W[u * UNITS + mt * 16 + c];   // RNE
                }
                dst[kt][mt] = v;
            }
    };

    f16x8 awh1[2][4], awx2[2][4], awh2[2][4];
    loadW(Wh1, awh1);
    loadW(Wx2, awx2);
    loadW(Wh2, awh2);

    f32x4 b2C[4];
#pragma unroll
    for (int mt = 0; mt < 4; ++mt)
#pragma unroll
        for (int r = 0; r < 4; ++r)
            b2C[mt][r] = b2[mt * 16 + q * 4 + r];

    // packed-half tanh coefficients (Taylor-5: x + x^3*(-1/3 + 2/15 x^2))
    const h2t kC1h = __builtin_amdgcn_cvt_pkrtz( 0.13333333f,  0.13333333f);
    const h2t kC0h = __builtin_amdgcn_cvt_pkrtz(-0.33333333f, -0.33333333f);

    auto tanh_pack4 = [&](f32x4 v) -> i32x2 {
        h2t lo = __builtin_amdgcn_cvt_pkrtz(v[0], v[1]);
        h2t hi = __builtin_amdgcn_cvt_pkrtz(v[2], v[3]);
        h2t ulo = lo * lo,           uhi = hi * hi;
        h2t wlo = ulo * lo,          whi = uhi * hi;
        h2t plo = ulo * kC1h + kC0h, phi = uhi * kC1h + kC0h;
        h2t rlo = wlo * plo + lo,    rhi = whi * phi + hi;
        i32x2 r;
        r[0] = __builtin_bit_cast(int, rlo);
        r[1] = __builtin_bit_cast(int, rhi);
        return r;
    };

    const int* tokC = &tokL[c][0];

    auto gatherXP = [&](int tk, f32x4 (&dst)[4]) {
        const float* p = xpT + (unsigned)tk * UNITS + q * 4;
        dst[0] = *reinterpret_cast<const f32x4*>(p);
        dst[1] = *reinterpret_cast<const f32x4*>(p + 16);
        dst[2] = *reinterpret_cast<const f32x4*>(p + 32);
        dst[3] = *reinterpret_cast<const f32x4*>(p + 48);
    };

    // state: h1 = h1(t-1), h2 = h2(t-2) entering iteration t (packed fp16)
    // tkNext = token for the xp row the NEXT prefetching body will gather
    i32x4 h1[2] = {(i32x4){0,0,0,0}, (i32x4){0,0,0,0}};
    i32x4 h2s[2] = {(i32x4){0,0,0,0}, (i32x4){0,0,0,0}};
    f32x4 xp0[4], xp1[4];
    int tkNext = 0;
    gatherXP(tokC[0], xp0);
    gatherXP(tokC[1], xp1);

    auto tanhP = [&](f32x4 (&a)[4], i32x4 (&h)[2]) {
        i32x2 p0 = tanh_pack4(a[0]), p1 = tanh_pack4(a[1]);
        i32x2 p2 = tanh_pack4(a[2]), p3 = tanh_pack4(a[3]);
        h[0] = (i32x4){p0[0], p0[1], p1[0], p1[1]};
        h[1] = (i32x4){p2[0], p2[1], p3[0], p3[1]};
    };

    // skewed body for iteration t (1 <= t <= 79):
    //   aL1 = xp(t) + Wh1^T h1(t-1)                 -> h1(t)
    //   aL2 = b2 + Wx2^T h1(t-1) + Wh2^T h2(t-2)    -> h2(t-1)
    // all 24 MFMAs depend only on PREVIOUS iterations' tanh outputs.
    auto body = [&](f32x4 (&xpS)[4], bool doPre, int tpn) {
        int tkUse = tkNext;              // tokC[t+2], loaded last iteration
        if (doPre) tkNext = tokC[tpn];   // ds_read lands by next iteration
        f32x4 aL1[4], aL2[4];
#pragma unroll
        for (int mt = 0; mt < 4; ++mt)
            aL1[mt] = __builtin_amdgcn_mfma_f32_16x16x32_f16(awh1[0][mt], ash(h1[0]), xpS[mt], 0, 0, 0);
#pragma unroll
        for (int mt = 0; mt < 4; ++mt)
            aL2[mt] = __builtin_amdgcn_mfma_f32_16x16x32_f16(awx2[0][mt], ash(h1[0]), b2C[mt], 0, 0, 0);
#pragma unroll
        for (int mt = 0; mt < 4; ++mt)
            aL1[mt] = __builtin_amdgcn_mfma_f32_16x16x32_f16(awh1[1][mt], ash(h1[1]), aL1[mt], 0, 0, 0);
#pragma unroll
        for (int mt = 0; mt < 4; ++mt)
            aL2[mt] = __builtin_amdgcn_mfma_f32_16x16x32_f16(awx2[1][mt], ash(h1[1]), aL2[mt], 0, 0, 0);
#pragma unroll
        for (int mt = 0; mt < 4; ++mt)
            aL2[mt] = __builtin_amdgcn_mfma_f32_16x16x32_f16(awh2[0][mt], ash(h2s[0]), aL2[mt], 0, 0, 0);
#pragma unroll
        for (int mt = 0; mt < 4; ++mt)
            aL2[mt] = __builtin_amdgcn_mfma_f32_16x16x32_f16(awh2[1][mt], ash(h2s[1]), aL2[mt], 0, 0, 0);
        if (doPre) gatherXP(tkUse, xpS);
        tanhP(aL1, h1);    // h1(t)
        tanhP(aL2, h2s);   // h2(t-1)
    };

    // ---- t = 0 peeled: layer 1 only (h2 state stays 0 == h2(-1)) ----
    {
        f32x4 aL1[4];
#pragma unroll
        for (int mt = 0; mt < 4; ++mt)
            aL1[mt] = __builtin_amdgcn_mfma_f32_16x16x32_f16(awh1[0][mt], ash(h1[0]), xp0[mt], 0, 0, 0);
#pragma unroll
        for (int mt = 0; mt < 4; ++mt)
            aL1[mt] = __builtin_amdgcn_mfma_f32_16x16x32_f16(awh1[1][mt], ash(h1[1]), aL1[mt], 0, 0, 0);
        gatherXP(tokC[2], xp0);
        tkNext = tokC[3];   // prime the prefetch register for body(1)
        tanhP(aL1, h1);     // h1(0)
    }

    // ---- t = 1..76 in parity pairs (xp(t) lives in buffer t&1) ----
    // body(t) consumes tokC[t+2] (pre-loaded), prefetches tokC[t+3].
#pragma unroll 1
    for (int tt = 1; tt <= 75; tt += 2) {
        body(xp1, true, tt + 3);   // t = tt   (odd):  uses xp1
        body(xp0, true, tt + 4);   // t = tt+1 (even): uses xp0
    }
    body(xp1, true, 80);   // t = 77: consumes tokC[79]; dummy-prefetch [80]
    body(xp0, false, 0);   // t = 78: uses xp(78)
    body(xp1, false, 0);   // t = 79: uses xp(79) -> h1(79), h2(78)

    // ---- epilogue: L2(79) + dense head, all in fp32 ----
    {
        f32x4 a[4];
#pragma unroll
        for (int mt = 0; mt < 4; ++mt)
            a[mt] = __builtin_amdgcn_mfma_f32_16x16x32_f16(awx2[0][mt], ash(h1[0]), b2C[mt], 0, 0, 0);
#pragma unroll
        for (int mt = 0; mt < 4; ++mt)
            a[mt] = __builtin_amdgcn_mfma_f32_16x16x32_f16(awx2[1][mt], ash(h1[1]), a[mt], 0, 0, 0);
#pragma unroll
        for (int mt = 0; mt < 4; ++mt)
            a[mt] = __builtin_amdgcn_mfma_f32_16x16x32_f16(awh2[0][mt], ash(h2s[0]), a[mt], 0, 0, 0);
#pragma unroll
        for (int mt = 0; mt < 4; ++mt)
            a[mt] = __builtin_amdgcn_mfma_f32_16x16x32_f16(awh2[1][mt], ash(h2s[1]), a[mt], 0, 0, 0);

        // head weights loaded only now (keeps steady-state VGPR pressure down)
        f32x4 wdC[4];
#pragma unroll
        for (int mt = 0; mt < 4; ++mt)
#pragma unroll
            for (int r = 0; r < 4; ++r)
                wdC[mt][r] = Wd[mt * 16 + q * 4 + r];
        const float bdv = bd[0];

        float p = 0.f;
#pragma unroll
        for (int mt = 0; mt < 4; ++mt) {
            f32x2 lo = tanh2((f32x2){a[mt][0], a[mt][1]});
            f32x2 hi = tanh2((f32x2){a[mt][2], a[mt][3]});
            p += lo[0] * wdC[mt][0] + lo[1] * wdC[mt][1]
               + hi[0] * wdC[mt][2] + hi[1] * wdC[mt][3];
        }
        p += __shfl_xor(p, 16);
        p += __shfl_xor(p, 32);
        if (q == 0) {
            float x = p + bdv;
            out[rowBase + c] = __builtin_amdgcn_rcpf(1.0f + __expf(-x));
        }
    }
}

extern "C" void kernel_launch(void* const* d_in, const int* in_sizes, int n_in,
                              void* d_out, int out_size, void* d_ws, size_t ws_size,
                              hipStream_t stream) {
    const int*   tokens = (const int*)  d_in[0];
    const float* emb    = (const float*)d_in[1];
    const float* Wx1    = (const float*)d_in[2];
    const float* Wh1    = (const float*)d_in[3];
    const float* b1     = (const float*)d_in[4];
    const float* Wx2    = (const float*)d_in[5];
    const float* Wh2    = (const float*)d_in[6];
    const float* b2     = (const float*)d_in[7];
    const float* Wd     = (const float*)d_in[8];
    const float* bd     = (const float*)d_in[9];
    float* out = (float*)d_out;

    // xp = emb@Wx1 + b1 (2.56 MB in d_ws; ws has held >= this in all rounds)
    float* xp = (float*)d_ws;
    xp_prep<<<dim3(VOCAB / 4), dim3(256), 0, stream>>>(emb, Wx1, b1, xp);

    dim3 grid(BATCH / ROWS);  // 1024 blocks x 1 wave = 1 wave/SIMD
    dim3 block(64);
    rnn_fused<<<grid, block, 0, stream>>>(tokens, xp, Wh1, Wx2, Wh2, b2, Wd, bd, out);
}